// Round 1
// baseline (709.766 us; speedup 1.0000x reference)
//
#include <hip/hip_runtime.h>
#include <hip/hip_cooperative_groups.h>
#include <math.h>

#define EPS  1e-7f
#define MAXT 0.999999f   // 1 - 1e-6

namespace cg = cooperative_groups;

typedef short  s16x8  __attribute__((ext_vector_type(8)));
typedef float  f32x16 __attribute__((ext_vector_type(16)));

__device__ __forceinline__ float waveRedSum(float v) {
    #pragma unroll
    for (int off = 32; off > 0; off >>= 1)
        v += __shfl_xor(v, off, 64);
    return v;
}

__device__ __forceinline__ unsigned short f2bf(float f) {
    unsigned u = __float_as_uint(f);
    u += 0x7fff + ((u >> 16) & 1);          // RNE, inputs are finite
    return (unsigned short)(u >> 16);
}

// phase-A tail: exp0 -> h_add(embed_bias) -> log0 -> pack bf16 (MFMA-B layout)
__device__ __forceinline__ void tangent_pack(float a0, float a1, float bx, float by,
                                             float y2, int row, int c0,
                                             unsigned short* __restrict__ vpack) {
    float np2 = waveRedSum(a0*a0 + a1*a1);
    float np  = fmaxf(sqrtf(np2), EPS);
    float se  = tanhf(np)/np;
    float h0 = a0*se, h1 = a1*se;
    float x2 = np2*se*se;
    float xy = waveRedSum(h0*bx + h1*by);
    float den = fmaxf(1.f + 2.f*xy + x2*y2, EPS);
    float cx = 1.f + 2.f*xy + y2;
    float cy = 1.f - x2;
    float hb0 = (cx*h0 + cy*bx)/den, hb1 = (cx*h1 + cy*by)/den;
    float m2 = waveRedSum(hb0*hb0 + hb1*hb1);
    float mm = fmaxf(sqrtf(m2), EPS);
    float sl = atanhf(fminf(mm, MAXT))/mm;
    const int tbase = (row >> 4)*2048 + (row & 15);
    vpack[tbase + c0*16]       = f2bf(hb0*sl);
    vpack[tbase + (c0+1)*16]   = f2bf(hb1*sl);
}

// phase-C tail: exp0 -> h_add(layer_bias) -> store
__device__ __forceinline__ void final_out(float a0, float a1, float bx, float by,
                                          float y2, int row, int c0,
                                          float* __restrict__ out) {
    float np2 = waveRedSum(a0*a0 + a1*a1);
    float np  = fmaxf(sqrtf(np2), EPS);
    float so  = tanhf(np)/np;
    float o0 = a0*so, o1 = a1*so;
    float x2 = np2*so*so;
    float xy = waveRedSum(o0*bx + o1*by);
    float den = fmaxf(1.f + 2.f*xy + x2*y2, EPS);
    float cx = 1.f + 2.f*xy + y2;
    float cy = 1.f - x2;
    float2 res;
    res.x = (cx*o0 + cy*bx)/den;
    res.y = (cx*o1 + cy*by)/den;
    *(float2*)(out + (size_t)row*128 + c0) = res;
}

// ---------------------------------------------------------------------------
// Fused persistent kernel. grid = 1024 blocks x 256 thr, 4 blocks/CU resident.
// Phase A: vpack = log0(h_add(exp0(log0(x)@embed), eb))  [2 rows/wave]
// Phase B: tpart[s] = adj[:, s-slice] @ v   (bf16 MFMA, split-K S=4)
// Phase C: out = h_add(exp0(log0([x ; exp0(sum tpart)]) @ layer), lb)
// ---------------------------------------------------------------------------
#define BK     128
#define SPLITS 4
#define KLEN   2048     // 8192 / SPLITS
#define NBLK   1024

__global__ __launch_bounds__(256, 4) void kFused(
        const float* __restrict__ x, const float* __restrict__ adj,
        const float* __restrict__ embed, const float* __restrict__ layer,
        const float* __restrict__ eb, const float* __restrict__ lb,
        float* __restrict__ out, unsigned short* __restrict__ vpack,
        float* __restrict__ tpart)
{
    __shared__ __align__(16) char smraw[32*(BK+8)*2];   // 8704 B, max over phases
    const int tid  = threadIdx.x;
    const int wave = tid >> 6;
    const int lane = tid & 63;
    const int c0   = lane*2;
    cg::grid_group grid = cg::this_grid();

    // ---------------- phase A: 8 rows/block, 2 rows/wave ----------------
    {
        float (*u)[2][128] = (float(*)[2][128])smraw;
        const int row0 = blockIdx.x*8 + wave;          // rows row0, row0+4
        float2 xr0 = *(const float2*)(x + (size_t)row0*128 + c0);
        float2 xr1 = *(const float2*)(x + (size_t)(row0+4)*128 + c0);
        float n20 = waveRedSum(xr0.x*xr0.x + xr0.y*xr0.y);
        float n21 = waveRedSum(xr1.x*xr1.x + xr1.y*xr1.y);
        float nn0 = fmaxf(sqrtf(n20), EPS), nn1 = fmaxf(sqrtf(n21), EPS);
        float s0 = atanhf(fminf(nn0, MAXT))/nn0;
        float s1 = atanhf(fminf(nn1, MAXT))/nn1;
        u[wave][0][c0] = xr0.x*s0; u[wave][0][c0+1] = xr0.y*s0;
        u[wave][1][c0] = xr1.x*s1; u[wave][1][c0+1] = xr1.y*s1;
        __syncthreads();
        float a00=0.f, a01=0.f, a10=0.f, a11=0.f;
        #pragma unroll 8
        for (int k = 0; k < 128; k++) {
            float uk0 = u[wave][0][k], uk1 = u[wave][1][k];
            float2 e  = *(const float2*)(embed + (size_t)k*128 + c0);
            a00 = fmaf(uk0, e.x, a00); a01 = fmaf(uk0, e.y, a01);
            a10 = fmaf(uk1, e.x, a10); a11 = fmaf(uk1, e.y, a11);
        }
        float bx = eb[c0], by = eb[c0+1];
        float y2 = waveRedSum(bx*bx + by*by);           // row-invariant
        tangent_pack(a00, a01, bx, by, y2, row0,     c0, vpack);
        tangent_pack(a10, a11, bx, by, y2, row0 + 4, c0, vpack);
    }

    grid.sync();   // vpack complete, device-visible

    // ---------------- phase B: 256 row-tiles x 4 K-splits ----------------
    {
        unsigned short (*As)[BK+8] = (unsigned short(*)[BK+8])smraw;
        const int bx = blockIdx.x & 255;
        const int by = blockIdx.x >> 8;
        const int r0 = bx*32;
        const int k0 = by*KLEN;
        float* tout  = tpart + (size_t)by * 8192 * 128;

        const int srow = tid >> 3;
        const int scol = (tid & 7) * 16;
        const float* aptr = adj + (size_t)(r0 + srow)*8192 + k0 + scol;

        const int m  = lane & 31;
        const int kh = lane >> 5;
        const int n  = wave*32 + m;
        const unsigned short* vb = vpack + (size_t)n*16 + kh*8;

        f32x16 acc = {0.f};

        float4 f0 = *(const float4*)(aptr + 0);
        float4 f1 = *(const float4*)(aptr + 4);
        float4 f2 = *(const float4*)(aptr + 8);
        float4 f3 = *(const float4*)(aptr + 12);

        const int kiters = KLEN / BK;   // 16
        for (int it = 0; it < kiters; it++) {
            __syncthreads();            // previous consumers done with As
            union { unsigned short u[8]; s16x8 v; } p0, p1;
            p0.u[0]=f2bf(f0.x); p0.u[1]=f2bf(f0.y); p0.u[2]=f2bf(f0.z); p0.u[3]=f2bf(f0.w);
            p0.u[4]=f2bf(f1.x); p0.u[5]=f2bf(f1.y); p0.u[6]=f2bf(f1.z); p0.u[7]=f2bf(f1.w);
            p1.u[0]=f2bf(f2.x); p1.u[1]=f2bf(f2.y); p1.u[2]=f2bf(f2.z); p1.u[3]=f2bf(f2.w);
            p1.u[4]=f2bf(f3.x); p1.u[5]=f2bf(f3.y); p1.u[6]=f2bf(f3.z); p1.u[7]=f2bf(f3.w);
            *(s16x8*)&As[srow][scol]     = p0.v;
            *(s16x8*)&As[srow][scol + 8] = p1.v;
            __syncthreads();

            if (it + 1 < kiters) {      // overlap next loads with MFMA
                aptr += BK;
                f0 = *(const float4*)(aptr + 0);
                f1 = *(const float4*)(aptr + 4);
                f2 = *(const float4*)(aptr + 8);
                f3 = *(const float4*)(aptr + 12);
            }

            const int ktile0 = (k0 + it*BK) >> 4;
            #pragma unroll
            for (int kk = 0; kk < BK/16; kk++) {
                s16x8 a = *(const s16x8*)&As[m][kk*16 + kh*8];
                s16x8 b = *(const s16x8*)(vb + (size_t)(ktile0 + kk)*2048);
                acc = __builtin_amdgcn_mfma_f32_32x32x16_bf16(a, b, acc, 0, 0, 0);
            }
        }

        // C/D layout: col = lane&31, row = (r&3) + 8*(r>>2) + 4*(lane>>5)
        #pragma unroll
        for (int r = 0; r < 16; r++) {
            int row = r0 + (r & 3) + 8*(r >> 2) + 4*kh;
            tout[(size_t)row*128 + n] = acc[r];
        }
    }

    grid.sync();   // tpart complete, device-visible

    // ---------------- phase C: 8 rows/block, 2 rows/wave ----------------
    {
        float (*w)[2][256] = (float(*)[2][256])smraw;
        const int row0 = blockIdx.x*8 + wave;
        #pragma unroll
        for (int r = 0; r < 2; r++) {
            const int row = row0 + 4*r;
            float2 tr = *(const float2*)(tpart + (size_t)row*128 + c0);
            #pragma unroll
            for (int s = 1; s < SPLITS; s++) {
                float2 p = *(const float2*)(tpart + (size_t)s*8192*128 + (size_t)row*128 + c0);
                tr.x += p.x; tr.y += p.y;
            }
            const float2 xr = *(const float2*)(x + (size_t)row*128 + c0);
            float st = waveRedSum(tr.x*tr.x + tr.y*tr.y);
            float sx = waveRedSum(xr.x*xr.x + xr.y*xr.y);
            float nt = fmaxf(sqrtf(st), EPS);
            float se = tanhf(nt)/nt;
            float ncat2 = sx + st*se*se;
            float ncat  = fmaxf(sqrtf(ncat2), EPS);
            float sw    = atanhf(fminf(ncat, MAXT))/ncat;
            w[wave][r][c0]           = xr.x*sw;
            w[wave][r][c0+1]         = xr.y*sw;
            w[wave][r][128 + c0]     = tr.x*se*sw;
            w[wave][r][128 + c0+1]   = tr.y*se*sw;
        }
        __syncthreads();
        float a00=0.f, a01=0.f, a10=0.f, a11=0.f;
        #pragma unroll 8
        for (int k = 0; k < 256; k++) {
            float wk0 = w[wave][0][k], wk1 = w[wave][1][k];
            float2 e  = *(const float2*)(layer + (size_t)k*128 + c0);
            a00 = fmaf(wk0, e.x, a00); a01 = fmaf(wk0, e.y, a01);
            a10 = fmaf(wk1, e.x, a10); a11 = fmaf(wk1, e.y, a11);
        }
        float bx = lb[c0], by = lb[c0+1];
        float y2 = waveRedSum(bx*bx + by*by);
        final_out(a00, a01, bx, by, y2, row0,     c0, out);
        final_out(a10, a11, bx, by, y2, row0 + 4, c0, out);
    }
}

// ===========================================================================
// Fallback path (proven 3-kernel pipeline) — used only if cooperative launch
// is rejected by the runtime/graph-capture.
// ===========================================================================
__global__ __launch_bounds__(256) void kA(const float* __restrict__ x,
                                          const float* __restrict__ embed,
                                          const float* __restrict__ ebias,
                                          unsigned short* __restrict__ vpack) {
    __shared__ float u[4][128];
    const int wave = threadIdx.x >> 6;
    const int lane = threadIdx.x & 63;
    const int row  = blockIdx.x * 4 + wave;
    const int c0   = lane * 2;

    const float2 xr = *(const float2*)(x + (size_t)row * 128 + c0);
    float n2 = waveRedSum(xr.x * xr.x + xr.y * xr.y);
    float n  = fmaxf(sqrtf(n2), EPS);
    float sc = atanhf(fminf(n, MAXT)) / n;
    u[wave][c0]     = xr.x * sc;
    u[wave][c0 + 1] = xr.y * sc;
    __syncthreads();

    float a0 = 0.f, a1 = 0.f;
    #pragma unroll 8
    for (int k = 0; k < 128; k++) {
        float  uk = u[wave][k];
        float2 e  = *(const float2*)(embed + (size_t)k * 128 + c0);
        a0 = fmaf(uk, e.x, a0);
        a1 = fmaf(uk, e.y, a1);
    }
    float bx = ebias[c0], by = ebias[c0 + 1];
    float y2 = waveRedSum(bx*bx + by*by);
    tangent_pack(a0, a1, bx, by, y2, row, c0, vpack);
}

__global__ __launch_bounds__(256) void kB(const float* __restrict__ adj,
                                          const unsigned short* __restrict__ vpack,
                                          float* __restrict__ tpart,
                                          int klen) {
    __shared__ __align__(16) unsigned short As[32][BK + 8];
    const int tid  = threadIdx.x;
    const int wave = tid >> 6;
    const int lane = tid & 63;
    const int r0   = blockIdx.x * 32;
    const int k0   = blockIdx.y * klen;
    float* tout    = tpart + (size_t)blockIdx.y * 8192 * 128;

    const int srow = tid >> 3;
    const int scol = (tid & 7) * 16;
    const float* aptr = adj + (size_t)(r0 + srow) * 8192 + k0 + scol;

    const int m  = lane & 31;
    const int kh = lane >> 5;
    const int n  = wave * 32 + m;
    const unsigned short* vb = vpack + (size_t)n * 16 + kh * 8;

    f32x16 acc = {0.f};
    float4 f0 = *(const float4*)(aptr + 0);
    float4 f1 = *(const float4*)(aptr + 4);
    float4 f2 = *(const float4*)(aptr + 8);
    float4 f3 = *(const float4*)(aptr + 12);

    const int kiters = klen / BK;
    for (int it = 0; it < kiters; it++) {
        __syncthreads();
        union { unsigned short u[8]; s16x8 v; } p0, p1;
        p0.u[0]=f2bf(f0.x); p0.u[1]=f2bf(f0.y); p0.u[2]=f2bf(f0.z); p0.u[3]=f2bf(f0.w);
        p0.u[4]=f2bf(f1.x); p0.u[5]=f2bf(f1.y); p0.u[6]=f2bf(f1.z); p0.u[7]=f2bf(f1.w);
        p1.u[0]=f2bf(f2.x); p1.u[1]=f2bf(f2.y); p1.u[2]=f2bf(f2.z); p1.u[3]=f2bf(f2.w);
        p1.u[4]=f2bf(f3.x); p1.u[5]=f2bf(f3.y); p1.u[6]=f2bf(f3.z); p1.u[7]=f2bf(f3.w);
        *(s16x8*)&As[srow][scol]     = p0.v;
        *(s16x8*)&As[srow][scol + 8] = p1.v;
        __syncthreads();

        if (it + 1 < kiters) {
            aptr += BK;
            f0 = *(const float4*)(aptr + 0);
            f1 = *(const float4*)(aptr + 4);
            f2 = *(const float4*)(aptr + 8);
            f3 = *(const float4*)(aptr + 12);
        }

        const int ktile0 = (k0 + it * BK) >> 4;
        #pragma unroll
        for (int kk = 0; kk < BK / 16; kk++) {
            s16x8 a = *(const s16x8*)&As[m][kk * 16 + kh * 8];
            s16x8 b = *(const s16x8*)(vb + (size_t)(ktile0 + kk) * 2048);
            acc = __builtin_amdgcn_mfma_f32_32x32x16_bf16(a, b, acc, 0, 0, 0);
        }
    }
    #pragma unroll
    for (int r = 0; r < 16; r++) {
        int row = r0 + (r & 3) + 8 * (r >> 2) + 4 * kh;
        tout[(size_t)row * 128 + n] = acc[r];
    }
}

__global__ __launch_bounds__(256) void kC(const float* __restrict__ x,
                                          const float* __restrict__ tpart,
                                          const float* __restrict__ layer,
                                          const float* __restrict__ lbias,
                                          float* __restrict__ out,
                                          int S) {
    __shared__ float w[4][256];
    const int wave = threadIdx.x >> 6;
    const int lane = threadIdx.x & 63;
    const int row  = blockIdx.x * 4 + wave;
    const int c0   = lane * 2;

    float2 tr = *(const float2*)(tpart + (size_t)row * 128 + c0);
    for (int s = 1; s < S; s++) {
        float2 p = *(const float2*)(tpart + (size_t)s * 8192 * 128 + (size_t)row * 128 + c0);
        tr.x += p.x; tr.y += p.y;
    }
    const float2 xr = *(const float2*)(x + (size_t)row * 128 + c0);
    float st = waveRedSum(tr.x * tr.x + tr.y * tr.y);
    float sx = waveRedSum(xr.x * xr.x + xr.y * xr.y);
    float nt = fmaxf(sqrtf(st), EPS);
    float se = tanhf(nt) / nt;
    float ncat2 = sx + st * se * se;
    float ncat  = fmaxf(sqrtf(ncat2), EPS);
    float sw    = atanhf(fminf(ncat, MAXT)) / ncat;
    w[wave][c0]           = xr.x * sw;
    w[wave][c0 + 1]       = xr.y * sw;
    w[wave][128 + c0]     = tr.x * se * sw;
    w[wave][128 + c0 + 1] = tr.y * se * sw;
    __syncthreads();

    float a0 = 0.f, a1 = 0.f;
    #pragma unroll 8
    for (int k = 0; k < 256; k++) {
        float  wk = w[wave][k];
        float2 e  = *(const float2*)(layer + (size_t)k * 128 + c0);
        a0 = fmaf(wk, e.x, a0);
        a1 = fmaf(wk, e.y, a1);
    }
    float bx = lbias[c0], by = lbias[c0 + 1];
    float y2 = waveRedSum(bx * bx + by * by);
    final_out(a0, a1, bx, by, y2, row, c0, out);
}

// ---------------------------------------------------------------------------
extern "C" void kernel_launch(void* const* d_in, const int* in_sizes, int n_in,
                              void* d_out, int out_size, void* d_ws, size_t ws_size,
                              hipStream_t stream) {
    const float* x     = (const float*)d_in[0];   // [8192,128]
    const float* adj   = (const float*)d_in[1];   // [8192,8192]
    const float* embed = (const float*)d_in[2];   // [128,128]
    const float* layer = (const float*)d_in[3];   // [256,128]
    const float* eb    = (const float*)d_in[4];   // [128]
    const float* lb    = (const float*)d_in[5];   // [128]
    float* out = (float*)d_out;

    const size_t vbytes = (size_t)8192 * 128 * 2;          // 2 MB bf16 packed
    unsigned short* vpack = (unsigned short*)d_ws;
    float* tpart = (float*)((char*)d_ws + vbytes);

    void* args[] = { (void*)&x, (void*)&adj, (void*)&embed, (void*)&layer,
                     (void*)&eb, (void*)&lb, (void*)&out, (void*)&vpack, (void*)&tpart };

    hipError_t err = hipLaunchCooperativeKernel(kFused, dim3(NBLK), dim3(256),
                                                args, 0u, stream);
    if (err != hipSuccess) {
        // proven 3-kernel path (S = 8 split-K)
        const int S = 8;
        kA<<<2048, 256, 0, stream>>>(x, embed, eb, vpack);
        kB<<<dim3(256, S), 256, 0, stream>>>(adj, vpack, tpart, 8192 / S);
        kC<<<2048, 256, 0, stream>>>(x, tpart, layer, lb, out, S);
    }
}

// Round 2
// 488.902 us; speedup vs baseline: 1.4518x; 1.4518x over previous
//
#include <hip/hip_runtime.h>
#include <math.h>

#define EPS  1e-7f
#define MAXT 0.999999f   // 1 - 1e-6

typedef short  s16x8  __attribute__((ext_vector_type(8)));
typedef float  f32x16 __attribute__((ext_vector_type(16)));

__device__ __forceinline__ float waveRedSum(float v) {
    #pragma unroll
    for (int off = 32; off > 0; off >>= 1)
        v += __shfl_xor(v, off, 64);
    return v;
}

__device__ __forceinline__ unsigned short f2bf(float f) {
    unsigned u = __float_as_uint(f);
    u += 0x7fff + ((u >> 16) & 1);          // RNE, inputs are finite
    return (unsigned short)(u >> 16);
}

// async 16B global->LDS DMA (dest = wave-uniform base + lane*16)
__device__ __forceinline__ void async_cp16(const float* src, void* ldsbase) {
    __builtin_amdgcn_global_load_lds(
        (const __attribute__((address_space(1))) unsigned int*)src,
        (__attribute__((address_space(3))) unsigned int*)ldsbase,
        16, 0, 0);
}

// phase-A tail: exp0 -> h_add(bias) -> log0 -> pack bf16 (MFMA-B layout)
__device__ __forceinline__ void tangent_pack(float a0, float a1, float bx, float by,
                                             float y2, int row, int c0,
                                             unsigned short* __restrict__ vpack) {
    float np2 = waveRedSum(a0*a0 + a1*a1);
    float np  = fmaxf(sqrtf(np2), EPS);
    float se  = tanhf(np)/np;
    float h0 = a0*se, h1 = a1*se;
    float x2 = np2*se*se;
    float xy = waveRedSum(h0*bx + h1*by);
    float den = fmaxf(1.f + 2.f*xy + x2*y2, EPS);
    float cx = 1.f + 2.f*xy + y2;
    float cy = 1.f - x2;
    float hb0 = (cx*h0 + cy*bx)/den, hb1 = (cx*h1 + cy*by)/den;
    float m2 = waveRedSum(hb0*hb0 + hb1*hb1);
    float mm = fmaxf(sqrtf(m2), EPS);
    float sl = atanhf(fminf(mm, MAXT))/mm;
    const int tbase = (row >> 4)*2048 + (row & 15);
    vpack[tbase + c0*16]       = f2bf(hb0*sl);
    vpack[tbase + (c0+1)*16]   = f2bf(hb1*sl);
}

// phase-C tail: exp0 -> h_add(bias) -> store
__device__ __forceinline__ void final_out(float a0, float a1, float bx, float by,
                                          float y2, int row, int c0,
                                          float* __restrict__ out) {
    float np2 = waveRedSum(a0*a0 + a1*a1);
    float np  = fmaxf(sqrtf(np2), EPS);
    float so  = tanhf(np)/np;
    float o0 = a0*so, o1 = a1*so;
    float x2 = np2*so*so;
    float xy = waveRedSum(o0*bx + o1*by);
    float den = fmaxf(1.f + 2.f*xy + x2*y2, EPS);
    float cx = 1.f + 2.f*xy + y2;
    float cy = 1.f - x2;
    float2 res;
    res.x = (cx*o0 + cy*bx)/den;
    res.y = (cx*o1 + cy*by)/den;
    *(float2*)(out + (size_t)row*128 + c0) = res;
}

// ---------------------------------------------------------------------------
// Kernel A: vpack = log0( h_add( exp0( log0(x) @ embed ), embed_bias ) )
// One wave per row; lane handles cols {2l, 2l+1}.
// ---------------------------------------------------------------------------
__global__ __launch_bounds__(256) void kA(const float* __restrict__ x,
                                          const float* __restrict__ embed,
                                          const float* __restrict__ ebias,
                                          unsigned short* __restrict__ vpack) {
    __shared__ float u[4][128];
    const int wave = threadIdx.x >> 6;
    const int lane = threadIdx.x & 63;
    const int row  = blockIdx.x * 4 + wave;
    const int c0   = lane * 2;

    const float2 xr = *(const float2*)(x + (size_t)row * 128 + c0);
    float n2 = waveRedSum(xr.x * xr.x + xr.y * xr.y);
    float n  = fmaxf(sqrtf(n2), EPS);
    float sc = atanhf(fminf(n, MAXT)) / n;
    u[wave][c0]     = xr.x * sc;
    u[wave][c0 + 1] = xr.y * sc;
    __syncthreads();

    float a0 = 0.f, a1 = 0.f;
    #pragma unroll 8
    for (int k = 0; k < 128; k++) {
        float  uk = u[wave][k];
        float2 e  = *(const float2*)(embed + (size_t)k * 128 + c0);
        a0 = fmaf(uk, e.x, a0);
        a1 = fmaf(uk, e.y, a1);
    }
    float bx = ebias[c0], by = ebias[c0 + 1];
    float y2 = waveRedSum(bx * bx + by * by);
    tangent_pack(a0, a1, bx, by, y2, row, c0, vpack);
}

// ---------------------------------------------------------------------------
// Kernel B v2: t = adj @ v  (bf16 MFMA, fp32 out), m97-style DMA pipeline.
//  - adj tile DMA'd HBM->LDS as fp32 via global_load_lds (width 16),
//    double-buffered; DMA drains only at the iter-end __syncthreads, so the
//    in-flight window is one full compute phase.
//  - LDS 16B chunks XOR-swizzled via the per-lane *global source* address
//    (linear DMA dest); reads apply the same XOR -> 8 lanes/16B-group
//    (structural optimum for wave64 ds_read_b128).
//  - B fragments preloaded *before* DMA issues each iter so their vmcnt
//    waits (in-order, oldest-first) never force the DMA to drain.
//  - bf16 convert on read (per-wave redundant, but VALU is cheap here).
// ---------------------------------------------------------------------------
#define BK 128

__global__ __launch_bounds__(256, 4) void kB(const float* __restrict__ adj,
                                             const unsigned short* __restrict__ vpack,
                                             float* __restrict__ tpart,
                                             int klen) {
    __shared__ __align__(16) float Af[2][32][128];   // 2 x 16 KB
    const int tid  = threadIdx.x;
    const int wave = tid >> 6;
    const int lane = tid & 63;
    const int r0   = blockIdx.x * 32;
    const int k0   = blockIdx.y * klen;
    float* tout    = tpart + (size_t)blockIdx.y * 8192 * 128;

    // DMA assignment: issue i = wave*4+j covers LDS rows {2i, 2i+1} (1 KB).
    // lane l lands at chunk (l&31) of row 2i+(l>>5); source chunk = dest^((row)&7).
    const int rpar = lane >> 5;
    const int cst  = lane & 31;

    // MFMA fragment indexing
    const int m  = lane & 31;       // A row / output row-within-tile
    const int kh = lane >> 5;       // k-half: k = kh*8 + j
    const int n  = wave * 32 + m;   // output col
    const int sw = m & 7;           // read-side chunk swizzle
    const unsigned short* vb = vpack + (size_t)n * 16 + kh * 8;

    f32x16 acc = {0.f};
    const int kiters = klen / BK;

    // prologue: DMA tile 0 -> buf 0
    #pragma unroll
    for (int j = 0; j < 4; j++) {
        int i = wave * 4 + j;
        int r = 2 * i + rpar;
        const float* src = adj + (size_t)(r0 + r) * 8192 + k0 + ((cst ^ (r & 7)) << 2);
        async_cp16(src, (char*)&Af[0][0][0] + i * 1024);
    }
    __syncthreads();

    for (int it = 0; it < kiters; it++) {
        const int cur = it & 1;
        const int ktile0 = (k0 + it * BK) >> 4;

        // (1) preload this tile's B fragments (oldest in vmcnt queue)
        s16x8 bfr[8];
        #pragma unroll
        for (int kk = 0; kk < 8; kk++)
            bfr[kk] = *(const s16x8*)(vb + (size_t)(ktile0 + kk) * 2048);

        // (2) issue DMA for tile it+1 into the other buffer
        //     (its previous readers all passed the barrier at end of it-1)
        if (it + 1 < kiters) {
            #pragma unroll
            for (int j = 0; j < 4; j++) {
                int i = wave * 4 + j;
                int r = 2 * i + rpar;
                const float* src = adj + (size_t)(r0 + r) * 8192 + k0 + (it + 1) * BK
                                 + ((cst ^ (r & 7)) << 2);
                async_cp16(src, (char*)&Af[cur ^ 1][0][0] + i * 1024);
            }
        }

        // (3) compute on buf cur (tile it): swizzled ds_read, cvt, MFMA
        #pragma unroll
        for (int kk = 0; kk < 8; kk++) {
            const int q0 = kk * 4 + kh * 2;
            const float4 lo = *(const float4*)&Af[cur][m][(q0 ^ sw) << 2];
            const float4 hi = *(const float4*)&Af[cur][m][((q0 + 1) ^ sw) << 2];
            union { unsigned short u[8]; s16x8 v; } p;
            p.u[0] = f2bf(lo.x); p.u[1] = f2bf(lo.y); p.u[2] = f2bf(lo.z); p.u[3] = f2bf(lo.w);
            p.u[4] = f2bf(hi.x); p.u[5] = f2bf(hi.y); p.u[6] = f2bf(hi.z); p.u[7] = f2bf(hi.w);
            acc = __builtin_amdgcn_mfma_f32_32x32x16_bf16(p.v, bfr[kk], acc, 0, 0, 0);
        }

        __syncthreads();   // drains DMA (vmcnt 0) + all readers done with cur
    }

    // epilogue: C/D layout col=lane&31, row=(r&3)+8*(r>>2)+4*(lane>>5)
    #pragma unroll
    for (int r = 0; r < 16; r++) {
        int row = r0 + (r & 3) + 8 * (r >> 2) + 4 * kh;
        tout[(size_t)row * 128 + n] = acc[r];
    }
}

// ---------------------------------------------------------------------------
// Kernel C: out = h_add( exp0( log0([x ; exp0(sum tpart)]) @ layer ), lbias )
// ---------------------------------------------------------------------------
__global__ __launch_bounds__(256) void kC(const float* __restrict__ x,
                                          const float* __restrict__ tpart,
                                          const float* __restrict__ layer,
                                          const float* __restrict__ lbias,
                                          float* __restrict__ out,
                                          int S) {
    __shared__ float w[4][256];
    const int wave = threadIdx.x >> 6;
    const int lane = threadIdx.x & 63;
    const int row  = blockIdx.x * 4 + wave;
    const int c0   = lane * 2;

    float2 tr = *(const float2*)(tpart + (size_t)row * 128 + c0);
    for (int s = 1; s < S; s++) {
        float2 p = *(const float2*)(tpart + (size_t)s * 8192 * 128 + (size_t)row * 128 + c0);
        tr.x += p.x; tr.y += p.y;
    }
    const float2 xr = *(const float2*)(x + (size_t)row * 128 + c0);
    float st = waveRedSum(tr.x * tr.x + tr.y * tr.y);
    float sx = waveRedSum(xr.x * xr.x + xr.y * xr.y);
    float nt = fmaxf(sqrtf(st), EPS);
    float se = tanhf(nt) / nt;
    float ncat2 = sx + st * se * se;
    float ncat  = fmaxf(sqrtf(ncat2), EPS);
    float sw    = atanhf(fminf(ncat, MAXT)) / ncat;
    w[wave][c0]           = xr.x * sw;
    w[wave][c0 + 1]       = xr.y * sw;
    w[wave][128 + c0]     = tr.x * se * sw;
    w[wave][128 + c0 + 1] = tr.y * se * sw;
    __syncthreads();

    float a0 = 0.f, a1 = 0.f;
    #pragma unroll 8
    for (int k = 0; k < 256; k++) {
        float  wk = w[wave][k];
        float2 e  = *(const float2*)(layer + (size_t)k * 128 + c0);
        a0 = fmaf(wk, e.x, a0);
        a1 = fmaf(wk, e.y, a1);
    }
    float bx = lbias[c0], by = lbias[c0 + 1];
    float y2 = waveRedSum(bx * bx + by * by);
    final_out(a0, a1, bx, by, y2, row, c0, out);
}

// ---------------------------------------------------------------------------
extern "C" void kernel_launch(void* const* d_in, const int* in_sizes, int n_in,
                              void* d_out, int out_size, void* d_ws, size_t ws_size,
                              hipStream_t stream) {
    const float* x     = (const float*)d_in[0];   // [8192,128]
    const float* adj   = (const float*)d_in[1];   // [8192,8192]
    const float* embed = (const float*)d_in[2];   // [128,128]
    const float* layer = (const float*)d_in[3];   // [256,128]
    const float* eb    = (const float*)d_in[4];   // [128]
    const float* lb    = (const float*)d_in[5];   // [128]
    float* out = (float*)d_out;

    const size_t vbytes = (size_t)8192 * 128 * 2;          // 2 MB bf16 packed
    unsigned short* vpack = (unsigned short*)d_ws;
    float* tpart = (float*)((char*)d_ws + vbytes);

    const int S = 8;                                        // split-K
    kA<<<2048, 256, 0, stream>>>(x, embed, eb, vpack);
    kB<<<dim3(256, S), 256, 0, stream>>>(adj, vpack, tpart, 8192 / S);
    kC<<<2048, 256, 0, stream>>>(x, tpart, layer, lb, out, S);
}

// Round 3
// 484.784 us; speedup vs baseline: 1.4641x; 1.0085x over previous
//
#include <hip/hip_runtime.h>
#include <math.h>

#define EPS  1e-7f
#define MAXT 0.999999f   // 1 - 1e-6

typedef short  s16x8  __attribute__((ext_vector_type(8)));
typedef float  f32x16 __attribute__((ext_vector_type(16)));

__device__ __forceinline__ float waveRedSum(float v) {
    #pragma unroll
    for (int off = 32; off > 0; off >>= 1)
        v += __shfl_xor(v, off, 64);
    return v;
}

__device__ __forceinline__ unsigned short f2bf(float f) {
    unsigned u = __float_as_uint(f);
    u += 0x7fff + ((u >> 16) & 1);          // RNE, inputs are finite
    return (unsigned short)(u >> 16);
}

// packed fp32x2 -> bf16x2 (RNE), single HW instruction on gfx950
__device__ __forceinline__ unsigned cvt_pk_bf16(float lo, float hi) {
    unsigned r;
    asm("v_cvt_pk_bf16_f32 %0, %1, %2" : "=v"(r) : "v"(lo), "v"(hi));
    return r;
}

// async 16B global->LDS DMA (dest = wave-uniform base + lane*16)
__device__ __forceinline__ void async_cp16(const float* src, void* ldsbase) {
    __builtin_amdgcn_global_load_lds(
        (const __attribute__((address_space(1))) unsigned int*)src,
        (__attribute__((address_space(3))) unsigned int*)ldsbase,
        16, 0, 0);
}

// phase-A tail: exp0 -> h_add(bias) -> log0 -> pack bf16 (MFMA-B layout)
__device__ __forceinline__ void tangent_pack(float a0, float a1, float bx, float by,
                                             float y2, int row, int c0,
                                             unsigned short* __restrict__ vpack) {
    float np2 = waveRedSum(a0*a0 + a1*a1);
    float np  = fmaxf(sqrtf(np2), EPS);
    float se  = tanhf(np)/np;
    float h0 = a0*se, h1 = a1*se;
    float x2 = np2*se*se;
    float xy = waveRedSum(h0*bx + h1*by);
    float den = fmaxf(1.f + 2.f*xy + x2*y2, EPS);
    float cx = 1.f + 2.f*xy + y2;
    float cy = 1.f - x2;
    float hb0 = (cx*h0 + cy*bx)/den, hb1 = (cx*h1 + cy*by)/den;
    float m2 = waveRedSum(hb0*hb0 + hb1*hb1);
    float mm = fmaxf(sqrtf(m2), EPS);
    float sl = atanhf(fminf(mm, MAXT))/mm;
    const int tbase = (row >> 4)*2048 + (row & 15);
    vpack[tbase + c0*16]       = f2bf(hb0*sl);
    vpack[tbase + (c0+1)*16]   = f2bf(hb1*sl);
}

// phase-C tail: exp0 -> h_add(bias) -> store
__device__ __forceinline__ void final_out(float a0, float a1, float bx, float by,
                                          float y2, int row, int c0,
                                          float* __restrict__ out) {
    float np2 = waveRedSum(a0*a0 + a1*a1);
    float np  = fmaxf(sqrtf(np2), EPS);
    float so  = tanhf(np)/np;
    float o0 = a0*so, o1 = a1*so;
    float x2 = np2*so*so;
    float xy = waveRedSum(o0*bx + o1*by);
    float den = fmaxf(1.f + 2.f*xy + x2*y2, EPS);
    float cx = 1.f + 2.f*xy + y2;
    float cy = 1.f - x2;
    float2 res;
    res.x = (cx*o0 + cy*bx)/den;
    res.y = (cx*o1 + cy*by)/den;
    *(float2*)(out + (size_t)row*128 + c0) = res;
}

// ---------------------------------------------------------------------------
// Kernel A: vpack = log0( h_add( exp0( log0(x) @ embed ), embed_bias ) )
// ---------------------------------------------------------------------------
__global__ __launch_bounds__(256) void kA(const float* __restrict__ x,
                                          const float* __restrict__ embed,
                                          const float* __restrict__ ebias,
                                          unsigned short* __restrict__ vpack) {
    __shared__ float u[4][128];
    const int wave = threadIdx.x >> 6;
    const int lane = threadIdx.x & 63;
    const int row  = blockIdx.x * 4 + wave;
    const int c0   = lane * 2;

    const float2 xr = *(const float2*)(x + (size_t)row * 128 + c0);
    float n2 = waveRedSum(xr.x * xr.x + xr.y * xr.y);
    float n  = fmaxf(sqrtf(n2), EPS);
    float sc = atanhf(fminf(n, MAXT)) / n;
    u[wave][c0]     = xr.x * sc;
    u[wave][c0 + 1] = xr.y * sc;
    __syncthreads();

    float a0 = 0.f, a1 = 0.f;
    #pragma unroll 8
    for (int k = 0; k < 128; k++) {
        float  uk = u[wave][k];
        float2 e  = *(const float2*)(embed + (size_t)k * 128 + c0);
        a0 = fmaf(uk, e.x, a0);
        a1 = fmaf(uk, e.y, a1);
    }
    float bx = ebias[c0], by = ebias[c0 + 1];
    float y2 = waveRedSum(bx * bx + by * by);
    tangent_pack(a0, a1, bx, by, y2, row, c0, vpack);
}

// ---------------------------------------------------------------------------
// Kernel B: t = adj @ v  (bf16 MFMA, fp32 out), DMA pipeline.
//  - adj tile DMA'd HBM->LDS as fp32 via global_load_lds (width 16), dbuf;
//    DMA drains only at the iter-end __syncthreads.
//  - 16B chunks XOR-swizzled via the per-lane *global source* address
//    (linear DMA dest); reads apply the same XOR.
//  - fp32 -> bf16 on read via v_cvt_pk_bf16_f32 (1 instr / 2 elems; was
//    ~5 VALU ops/elem of hand-rolled RNE — pack cost down ~10x).
//  - B fragments preloaded before DMA issue so their vmcnt waits never
//    force the DMA queue (in-order, oldest-first) to drain.
// ---------------------------------------------------------------------------
#define BK 128

__global__ __launch_bounds__(256, 4) void kB(const float* __restrict__ adj,
                                             const unsigned short* __restrict__ vpack,
                                             float* __restrict__ tpart,
                                             int klen) {
    __shared__ __align__(16) float Af[2][32][128];   // 2 x 16 KB
    const int tid  = threadIdx.x;
    const int wave = tid >> 6;
    const int lane = tid & 63;
    const int r0   = blockIdx.x * 32;
    const int k0   = blockIdx.y * klen;
    float* tout    = tpart + (size_t)blockIdx.y * 8192 * 128;

    // DMA: issue i = wave*4+j covers LDS rows {2i, 2i+1} (1 KB each issue).
    const int rpar = lane >> 5;
    const int cst  = lane & 31;

    // MFMA fragment indexing
    const int m  = lane & 31;       // A row / output row-within-tile
    const int kh = lane >> 5;       // k-half: k = kh*8 + j
    const int n  = wave * 32 + m;   // output col
    const int sw = m & 7;           // read-side chunk swizzle
    const unsigned short* vb = vpack + (size_t)n * 16 + kh * 8;

    f32x16 acc = {0.f};
    const int kiters = klen / BK;

    // prologue: DMA tile 0 -> buf 0
    #pragma unroll
    for (int j = 0; j < 4; j++) {
        int i = wave * 4 + j;
        int r = 2 * i + rpar;
        const float* src = adj + (size_t)(r0 + r) * 8192 + k0 + ((cst ^ (r & 7)) << 2);
        async_cp16(src, (char*)&Af[0][0][0] + i * 1024);
    }
    __syncthreads();

    for (int it = 0; it < kiters; it++) {
        const int cur = it & 1;
        const int ktile0 = (k0 + it * BK) >> 4;

        // (1) preload this tile's B fragments (oldest in vmcnt queue)
        s16x8 bfr[8];
        #pragma unroll
        for (int kk = 0; kk < 8; kk++)
            bfr[kk] = *(const s16x8*)(vb + (size_t)(ktile0 + kk) * 2048);

        // (2) issue DMA for tile it+1 into the other buffer
        if (it + 1 < kiters) {
            #pragma unroll
            for (int j = 0; j < 4; j++) {
                int i = wave * 4 + j;
                int r = 2 * i + rpar;
                const float* src = adj + (size_t)(r0 + r) * 8192 + k0 + (it + 1) * BK
                                 + ((cst ^ (r & 7)) << 2);
                async_cp16(src, (char*)&Af[cur ^ 1][0][0] + i * 1024);
            }
        }

        // (3) compute on buf cur: swizzled ds_read, cvt_pk, MFMA
        #pragma unroll
        for (int kk = 0; kk < 8; kk++) {
            const int q0 = kk * 4 + kh * 2;
            const float4 lo = *(const float4*)&Af[cur][m][(q0 ^ sw) << 2];
            const float4 hi = *(const float4*)&Af[cur][m][((q0 + 1) ^ sw) << 2];
            union { unsigned u[4]; s16x8 v; } p;
            p.u[0] = cvt_pk_bf16(lo.x, lo.y);
            p.u[1] = cvt_pk_bf16(lo.z, lo.w);
            p.u[2] = cvt_pk_bf16(hi.x, hi.y);
            p.u[3] = cvt_pk_bf16(hi.z, hi.w);
            acc = __builtin_amdgcn_mfma_f32_32x32x16_bf16(p.v, bfr[kk], acc, 0, 0, 0);
        }

        __syncthreads();   // drains DMA (vmcnt 0) + all readers done with cur
    }

    // epilogue: C/D layout col=lane&31, row=(r&3)+8*(r>>2)+4*(lane>>5)
    #pragma unroll
    for (int r = 0; r < 16; r++) {
        int row = r0 + (r & 3) + 8 * (r >> 2) + 4 * kh;
        tout[(size_t)row * 128 + n] = acc[r];
    }
}

// ---------------------------------------------------------------------------
// Kernel C: out = h_add( exp0( log0([x ; exp0(sum tpart)]) @ layer ), lbias )
// ---------------------------------------------------------------------------
__global__ __launch_bounds__(256) void kC(const float* __restrict__ x,
                                          const float* __restrict__ tpart,
                                          const float* __restrict__ layer,
                                          const float* __restrict__ lbias,
                                          float* __restrict__ out,
                                          int S) {
    __shared__ float w[4][256];
    const int wave = threadIdx.x >> 6;
    const int lane = threadIdx.x & 63;
    const int row  = blockIdx.x * 4 + wave;
    const int c0   = lane * 2;

    float2 tr = *(const float2*)(tpart + (size_t)row * 128 + c0);
    for (int s = 1; s < S; s++) {
        float2 p = *(const float2*)(tpart + (size_t)s * 8192 * 128 + (size_t)row * 128 + c0);
        tr.x += p.x; tr.y += p.y;
    }
    const float2 xr = *(const float2*)(x + (size_t)row * 128 + c0);
    float st = waveRedSum(tr.x * tr.x + tr.y * tr.y);
    float sx = waveRedSum(xr.x * xr.x + xr.y * xr.y);
    float nt = fmaxf(sqrtf(st), EPS);
    float se = tanhf(nt) / nt;
    float ncat2 = sx + st * se * se;
    float ncat  = fmaxf(sqrtf(ncat2), EPS);
    float sw    = atanhf(fminf(ncat, MAXT)) / ncat;
    w[wave][c0]           = xr.x * sw;
    w[wave][c0 + 1]       = xr.y * sw;
    w[wave][128 + c0]     = tr.x * se * sw;
    w[wave][128 + c0 + 1] = tr.y * se * sw;
    __syncthreads();

    float a0 = 0.f, a1 = 0.f;
    #pragma unroll 8
    for (int k = 0; k < 256; k++) {
        float  wk = w[wave][k];
        float2 e  = *(const float2*)(layer + (size_t)k * 128 + c0);
        a0 = fmaf(wk, e.x, a0);
        a1 = fmaf(wk, e.y, a1);
    }
    float bx = lbias[c0], by = lbias[c0 + 1];
    float y2 = waveRedSum(bx * bx + by * by);
    final_out(a0, a1, bx, by, y2, row, c0, out);
}

// ---------------------------------------------------------------------------
extern "C" void kernel_launch(void* const* d_in, const int* in_sizes, int n_in,
                              void* d_out, int out_size, void* d_ws, size_t ws_size,
                              hipStream_t stream) {
    const float* x     = (const float*)d_in[0];   // [8192,128]
    const float* adj   = (const float*)d_in[1];   // [8192,8192]
    const float* embed = (const float*)d_in[2];   // [128,128]
    const float* layer = (const float*)d_in[3];   // [256,128]
    const float* eb    = (const float*)d_in[4];   // [128]
    const float* lb    = (const float*)d_in[5];   // [128]
    float* out = (float*)d_out;

    const size_t vbytes = (size_t)8192 * 128 * 2;          // 2 MB bf16 packed
    unsigned short* vpack = (unsigned short*)d_ws;
    float* tpart = (float*)((char*)d_ws + vbytes);

    const int S = 8;                                        // split-K
    kA<<<2048, 256, 0, stream>>>(x, embed, eb, vpack);
    kB<<<dim3(256, S), 256, 0, stream>>>(adj, vpack, tpart, 8192 / S);
    kC<<<2048, 256, 0, stream>>>(x, tpart, layer, lb, out, S);
}

// Round 5
// 444.209 us; speedup vs baseline: 1.5978x; 1.0913x over previous
//
#include <hip/hip_runtime.h>
#include <math.h>

#define EPS  1e-7f
#define MAXT 0.999999f   // 1 - 1e-6

typedef short  s16x8  __attribute__((ext_vector_type(8)));
typedef float  f32x16 __attribute__((ext_vector_type(16)));

__device__ __forceinline__ float waveRedSum(float v) {
    #pragma unroll
    for (int off = 32; off > 0; off >>= 1)
        v += __shfl_xor(v, off, 64);
    return v;
}

__device__ __forceinline__ unsigned short f2bf(float f) {
    unsigned u = __float_as_uint(f);
    u += 0x7fff + ((u >> 16) & 1);          // RNE, inputs are finite
    return (unsigned short)(u >> 16);
}

// packed fp32x2 -> bf16x2 (RNE), single HW instruction on gfx950
__device__ __forceinline__ unsigned cvt_pk_bf16(float lo, float hi) {
    unsigned r;
    asm("v_cvt_pk_bf16_f32 %0, %1, %2" : "=v"(r) : "v"(lo), "v"(hi));
    return r;
}

// async 16B global->LDS DMA (dest = wave-uniform base + lane*16)
__device__ __forceinline__ void async_cp16(const float* src, void* ldsbase) {
    __builtin_amdgcn_global_load_lds(
        (const __attribute__((address_space(1))) unsigned int*)src,
        (__attribute__((address_space(3))) unsigned int*)ldsbase,
        16, 0, 0);
}

// phase-A tail: exp0 -> h_add(bias) -> log0 -> pack bf16 (MFMA-B layout)
__device__ __forceinline__ void tangent_pack(float a0, float a1, float bx, float by,
                                             float y2, int row, int c0,
                                             unsigned short* __restrict__ vpack) {
    float np2 = waveRedSum(a0*a0 + a1*a1);
    float np  = fmaxf(sqrtf(np2), EPS);
    float se  = tanhf(np)/np;
    float h0 = a0*se, h1 = a1*se;
    float x2 = np2*se*se;
    float xy = waveRedSum(h0*bx + h1*by);
    float den = fmaxf(1.f + 2.f*xy + x2*y2, EPS);
    float cx = 1.f + 2.f*xy + y2;
    float cy = 1.f - x2;
    float hb0 = (cx*h0 + cy*bx)/den, hb1 = (cx*h1 + cy*by)/den;
    float m2 = waveRedSum(hb0*hb0 + hb1*hb1);
    float mm = fmaxf(sqrtf(m2), EPS);
    float sl = atanhf(fminf(mm, MAXT))/mm;
    const int tbase = (row >> 4)*2048 + (row & 15);
    vpack[tbase + c0*16]       = f2bf(hb0*sl);
    vpack[tbase + (c0+1)*16]   = f2bf(hb1*sl);
}

// phase-C tail: exp0 -> h_add(bias) -> store
__device__ __forceinline__ void final_out(float a0, float a1, float bx, float by,
                                          float y2, int row, int c0,
                                          float* __restrict__ out) {
    float np2 = waveRedSum(a0*a0 + a1*a1);
    float np  = fmaxf(sqrtf(np2), EPS);
    float so  = tanhf(np)/np;
    float o0 = a0*so, o1 = a1*so;
    float x2 = np2*so*so;
    float xy = waveRedSum(o0*bx + o1*by);
    float den = fmaxf(1.f + 2.f*xy + x2*y2, EPS);
    float cx = 1.f + 2.f*xy + y2;
    float cy = 1.f - x2;
    float2 res;
    res.x = (cx*o0 + cy*bx)/den;
    res.y = (cx*o1 + cy*by)/den;
    *(float2*)(out + (size_t)row*128 + c0) = res;
}

// ---------------------------------------------------------------------------
// Kernel A: vpack = log0( h_add( exp0( log0(x) @ embed ), embed_bias ) )
// 2 rows/wave: halves embed L2 traffic (512 -> 256 MB) and wave count.
// ---------------------------------------------------------------------------
__global__ __launch_bounds__(256) void kA(const float* __restrict__ x,
                                          const float* __restrict__ embed,
                                          const float* __restrict__ ebias,
                                          unsigned short* __restrict__ vpack) {
    __shared__ float u[4][2][128];
    const int wave = threadIdx.x >> 6;
    const int lane = threadIdx.x & 63;
    const int row0 = blockIdx.x * 8 + wave;       // rows row0, row0+4
    const int c0   = lane * 2;

    float2 xr0 = *(const float2*)(x + (size_t)row0 * 128 + c0);
    float2 xr1 = *(const float2*)(x + (size_t)(row0 + 4) * 128 + c0);
    float n20 = waveRedSum(xr0.x*xr0.x + xr0.y*xr0.y);
    float n21 = waveRedSum(xr1.x*xr1.x + xr1.y*xr1.y);
    float nn0 = fmaxf(sqrtf(n20), EPS), nn1 = fmaxf(sqrtf(n21), EPS);
    float s0 = atanhf(fminf(nn0, MAXT))/nn0;
    float s1 = atanhf(fminf(nn1, MAXT))/nn1;
    u[wave][0][c0] = xr0.x*s0; u[wave][0][c0+1] = xr0.y*s0;
    u[wave][1][c0] = xr1.x*s1; u[wave][1][c0+1] = xr1.y*s1;
    __syncthreads();

    float a00=0.f, a01=0.f, a10=0.f, a11=0.f;
    #pragma unroll 8
    for (int k = 0; k < 128; k++) {
        float uk0 = u[wave][0][k], uk1 = u[wave][1][k];
        float2 e  = *(const float2*)(embed + (size_t)k * 128 + c0);
        a00 = fmaf(uk0, e.x, a00); a01 = fmaf(uk0, e.y, a01);
        a10 = fmaf(uk1, e.x, a10); a11 = fmaf(uk1, e.y, a11);
    }
    float bx = ebias[c0], by = ebias[c0 + 1];
    float y2 = waveRedSum(bx*bx + by*by);          // row-invariant
    tangent_pack(a00, a01, bx, by, y2, row0,     c0, vpack);
    tangent_pack(a10, a11, bx, by, y2, row0 + 4, c0, vpack);
}

// ---------------------------------------------------------------------------
// Kernel B: t = adj @ v  (bf16 MFMA, fp32 out), DMA pipeline.
// EXACT round-3 verified structure (round-4's restructure raced/miscompiled):
//  - adj tile DMA'd HBM->LDS as fp32 (global_load_lds width 16), dbuf;
//    DMA drains only at the iter-end __syncthreads.
//  - 16B chunks XOR-swizzled via the per-lane *global source* address
//    (linear DMA dest); reads apply the same XOR.
//  - fp32 -> bf16 on read via v_cvt_pk_bf16_f32.
//  - B fragments preloaded before DMA issue so their vmcnt waits never
//    force the DMA queue (in-order, oldest-first) to drain.
// ---------------------------------------------------------------------------
#define BK 128

__global__ __launch_bounds__(256, 4) void kB(const float* __restrict__ adj,
                                             const unsigned short* __restrict__ vpack,
                                             float* __restrict__ tpart,
                                             int klen) {
    __shared__ __align__(16) float Af[2][32][128];   // 2 x 16 KB
    const int tid  = threadIdx.x;
    const int wave = tid >> 6;
    const int lane = tid & 63;
    const int r0   = blockIdx.x * 32;
    const int k0   = blockIdx.y * klen;
    float* tout    = tpart + (size_t)blockIdx.y * 8192 * 128;

    // DMA: issue i = wave*4+j covers LDS rows {2i, 2i+1} (1 KB each issue).
    const int rpar = lane >> 5;
    const int cst  = lane & 31;

    // MFMA fragment indexing
    const int m  = lane & 31;       // A row / output row-within-tile
    const int kh = lane >> 5;       // k-half
    const int n  = wave * 32 + m;   // output col
    const int sw = m & 7;           // read-side chunk swizzle
    const unsigned short* vb = vpack + (size_t)n * 16 + kh * 8;

    f32x16 acc = {0.f};
    const int kiters = klen / BK;

    // prologue: DMA tile 0 -> buf 0
    #pragma unroll
    for (int j = 0; j < 4; j++) {
        int i = wave * 4 + j;
        int r = 2 * i + rpar;
        const float* src = adj + (size_t)(r0 + r) * 8192 + k0 + ((cst ^ (r & 7)) << 2);
        async_cp16(src, (char*)&Af[0][0][0] + i * 1024);
    }
    __syncthreads();

    for (int it = 0; it < kiters; it++) {
        const int cur = it & 1;
        const int ktile0 = (k0 + it * BK) >> 4;

        // (1) preload this tile's B fragments (oldest in vmcnt queue)
        s16x8 bfr[8];
        #pragma unroll
        for (int kk = 0; kk < 8; kk++)
            bfr[kk] = *(const s16x8*)(vb + (size_t)(ktile0 + kk) * 2048);

        // (2) issue DMA for tile it+1 into the other buffer
        if (it + 1 < kiters) {
            #pragma unroll
            for (int j = 0; j < 4; j++) {
                int i = wave * 4 + j;
                int r = 2 * i + rpar;
                const float* src = adj + (size_t)(r0 + r) * 8192 + k0 + (it + 1) * BK
                                 + ((cst ^ (r & 7)) << 2);
                async_cp16(src, (char*)&Af[cur ^ 1][0][0] + i * 1024);
            }
        }

        // (3) compute on buf cur: swizzled ds_read, cvt_pk, MFMA
        #pragma unroll
        for (int kk = 0; kk < 8; kk++) {
            const int q0 = kk * 4 + kh * 2;
            const float4 lo = *(const float4*)&Af[cur][m][(q0 ^ sw) << 2];
            const float4 hi = *(const float4*)&Af[cur][m][((q0 + 1) ^ sw) << 2];
            union { unsigned u[4]; s16x8 v; } p;
            p.u[0] = cvt_pk_bf16(lo.x, lo.y);
            p.u[1] = cvt_pk_bf16(lo.z, lo.w);
            p.u[2] = cvt_pk_bf16(hi.x, hi.y);
            p.u[3] = cvt_pk_bf16(hi.z, hi.w);
            acc = __builtin_amdgcn_mfma_f32_32x32x16_bf16(p.v, bfr[kk], acc, 0, 0, 0);
        }

        __syncthreads();   // drains DMA (vmcnt 0) + all readers done with cur
    }

    // epilogue: C/D layout col=lane&31, row=(r&3)+8*(r>>2)+4*(lane>>5)
    #pragma unroll
    for (int r = 0; r < 16; r++) {
        int row = r0 + (r & 3) + 8 * (r >> 2) + 4 * kh;
        tout[(size_t)row * 128 + n] = acc[r];
    }
}

// ---------------------------------------------------------------------------
// Kernel C: out = h_add( exp0( log0([x ; exp0(sum tpart)]) @ layer ), lbias )
// 2 rows/wave: halves layer L2 traffic (1 GB -> 512 MB).
// ---------------------------------------------------------------------------
#define SPLITS 8

__global__ __launch_bounds__(256) void kC(const float* __restrict__ x,
                                          const float* __restrict__ tpart,
                                          const float* __restrict__ layer,
                                          const float* __restrict__ lbias,
                                          float* __restrict__ out) {
    __shared__ float w[4][2][256];
    const int wave = threadIdx.x >> 6;
    const int lane = threadIdx.x & 63;
    const int row0 = blockIdx.x * 8 + wave;       // rows row0, row0+4
    const int c0   = lane * 2;

    #pragma unroll
    for (int r = 0; r < 2; r++) {
        const int row = row0 + 4 * r;
        float2 tr = *(const float2*)(tpart + (size_t)row * 128 + c0);
        #pragma unroll
        for (int s = 1; s < SPLITS; s++) {
            float2 p = *(const float2*)(tpart + (size_t)s * 8192 * 128
                                        + (size_t)row * 128 + c0);
            tr.x += p.x; tr.y += p.y;
        }
        const float2 xr = *(const float2*)(x + (size_t)row * 128 + c0);
        float st = waveRedSum(tr.x*tr.x + tr.y*tr.y);
        float sx = waveRedSum(xr.x*xr.x + xr.y*xr.y);
        float nt = fmaxf(sqrtf(st), EPS);
        float se = tanhf(nt)/nt;
        float ncat2 = sx + st*se*se;
        float ncat  = fmaxf(sqrtf(ncat2), EPS);
        float swl   = atanhf(fminf(ncat, MAXT))/ncat;
        w[wave][r][c0]         = xr.x*swl;
        w[wave][r][c0+1]       = xr.y*swl;
        w[wave][r][128 + c0]   = tr.x*se*swl;
        w[wave][r][128 + c0+1] = tr.y*se*swl;
    }
    __syncthreads();

    float a00=0.f, a01=0.f, a10=0.f, a11=0.f;
    #pragma unroll 8
    for (int k = 0; k < 256; k++) {
        float wk0 = w[wave][0][k], wk1 = w[wave][1][k];
        float2 e  = *(const float2*)(layer + (size_t)k * 128 + c0);
        a00 = fmaf(wk0, e.x, a00); a01 = fmaf(wk0, e.y, a01);
        a10 = fmaf(wk1, e.x, a10); a11 = fmaf(wk1, e.y, a11);
    }
    float bx = lbias[c0], by = lbias[c0 + 1];
    float y2 = waveRedSum(bx*bx + by*by);
    final_out(a00, a01, bx, by, y2, row0,     c0, out);
    final_out(a10, a11, bx, by, y2, row0 + 4, c0, out);
}

// ---------------------------------------------------------------------------
extern "C" void kernel_launch(void* const* d_in, const int* in_sizes, int n_in,
                              void* d_out, int out_size, void* d_ws, size_t ws_size,
                              hipStream_t stream) {
    const float* x     = (const float*)d_in[0];   // [8192,128]
    const float* adj   = (const float*)d_in[1];   // [8192,8192]
    const float* embed = (const float*)d_in[2];   // [128,128]
    const float* layer = (const float*)d_in[3];   // [256,128]
    const float* eb    = (const float*)d_in[4];   // [128]
    const float* lb    = (const float*)d_in[5];   // [128]
    float* out = (float*)d_out;

    const size_t vbytes = (size_t)8192 * 128 * 2;          // 2 MB bf16 packed
    unsigned short* vpack = (unsigned short*)d_ws;
    float* tpart = (float*)((char*)d_ws + vbytes);

    kA<<<1024, 256, 0, stream>>>(x, embed, eb, vpack);
    kB<<<dim3(256, SPLITS), 256, 0, stream>>>(adj, vpack, tpart, 8192 / SPLITS);
    kC<<<1024, 256, 0, stream>>>(x, tpart, layer, lb, out);
}

// Round 6
// 427.194 us; speedup vs baseline: 1.6615x; 1.0398x over previous
//
#include <hip/hip_runtime.h>
#include <math.h>

#define EPS  1e-7f
#define MAXT 0.999999f   // 1 - 1e-6

typedef short  s16x8  __attribute__((ext_vector_type(8)));
typedef float  f32x16 __attribute__((ext_vector_type(16)));

__device__ __forceinline__ float waveRedSum(float v) {
    #pragma unroll
    for (int off = 32; off > 0; off >>= 1)
        v += __shfl_xor(v, off, 64);
    return v;
}

__device__ __forceinline__ unsigned short f2bf(float f) {
    unsigned u = __float_as_uint(f);
    u += 0x7fff + ((u >> 16) & 1);          // RNE, inputs are finite
    return (unsigned short)(u >> 16);
}

// packed fp32x2 -> bf16x2 (RNE), single HW instruction on gfx950
__device__ __forceinline__ unsigned cvt_pk_bf16(float lo, float hi) {
    unsigned r;
    asm("v_cvt_pk_bf16_f32 %0, %1, %2" : "=v"(r) : "v"(lo), "v"(hi));
    return r;
}

// async 16B global->LDS DMA (dest = wave-uniform base + lane*16)
__device__ __forceinline__ void async_cp16(const float* src, void* ldsbase) {
    __builtin_amdgcn_global_load_lds(
        (const __attribute__((address_space(1))) unsigned int*)src,
        (__attribute__((address_space(3))) unsigned int*)ldsbase,
        16, 0, 0);
}

// phase-A tail: exp0 -> h_add(bias) -> log0 -> pack bf16 (MFMA-B layout)
__device__ __forceinline__ void tangent_pack(float a0, float a1, float bx, float by,
                                             float y2, int row, int c0,
                                             unsigned short* __restrict__ vpack) {
    float np2 = waveRedSum(a0*a0 + a1*a1);
    float np  = fmaxf(sqrtf(np2), EPS);
    float se  = tanhf(np)/np;
    float h0 = a0*se, h1 = a1*se;
    float x2 = np2*se*se;
    float xy = waveRedSum(h0*bx + h1*by);
    float den = fmaxf(1.f + 2.f*xy + x2*y2, EPS);
    float cx = 1.f + 2.f*xy + y2;
    float cy = 1.f - x2;
    float hb0 = (cx*h0 + cy*bx)/den, hb1 = (cx*h1 + cy*by)/den;
    float m2 = waveRedSum(hb0*hb0 + hb1*hb1);
    float mm = fmaxf(sqrtf(m2), EPS);
    float sl = atanhf(fminf(mm, MAXT))/mm;
    const int tbase = (row >> 4)*2048 + (row & 15);
    vpack[tbase + c0*16]       = f2bf(hb0*sl);
    vpack[tbase + (c0+1)*16]   = f2bf(hb1*sl);
}

// phase-C tail: exp0 -> h_add(bias) -> store
__device__ __forceinline__ void final_out(float a0, float a1, float bx, float by,
                                          float y2, int row, int c0,
                                          float* __restrict__ out) {
    float np2 = waveRedSum(a0*a0 + a1*a1);
    float np  = fmaxf(sqrtf(np2), EPS);
    float so  = tanhf(np)/np;
    float o0 = a0*so, o1 = a1*so;
    float x2 = np2*so*so;
    float xy = waveRedSum(o0*bx + o1*by);
    float den = fmaxf(1.f + 2.f*xy + x2*y2, EPS);
    float cx = 1.f + 2.f*xy + y2;
    float cy = 1.f - x2;
    float2 res;
    res.x = (cx*o0 + cy*bx)/den;
    res.y = (cx*o1 + cy*by)/den;
    *(float2*)(out + (size_t)row*128 + c0) = res;
}

// ---------------------------------------------------------------------------
// Kernel A: vpack = log0( h_add( exp0( log0(x) @ embed ), embed_bias ) )
// 4 rows/wave: quarters embed L2 traffic (512 -> 128 MB vs 1-row) and waves.
// ---------------------------------------------------------------------------
__global__ __launch_bounds__(256) void kA(const float* __restrict__ x,
                                          const float* __restrict__ embed,
                                          const float* __restrict__ ebias,
                                          unsigned short* __restrict__ vpack) {
    __shared__ float u[4][4][128];
    const int wave = threadIdx.x >> 6;
    const int lane = threadIdx.x & 63;
    const int row0 = blockIdx.x * 16 + wave * 4;   // rows row0 .. row0+3
    const int c0   = lane * 2;

    #pragma unroll
    for (int r = 0; r < 4; r++) {
        const int row = row0 + r;
        float2 xr = *(const float2*)(x + (size_t)row * 128 + c0);
        float n2 = waveRedSum(xr.x*xr.x + xr.y*xr.y);
        float nn = fmaxf(sqrtf(n2), EPS);
        float sc = atanhf(fminf(nn, MAXT))/nn;
        u[wave][r][c0]     = xr.x*sc;
        u[wave][r][c0 + 1] = xr.y*sc;
    }
    __syncthreads();

    float a0[4] = {0.f,0.f,0.f,0.f}, a1[4] = {0.f,0.f,0.f,0.f};
    #pragma unroll 8
    for (int k = 0; k < 128; k++) {
        float2 e = *(const float2*)(embed + (size_t)k * 128 + c0);
        #pragma unroll
        for (int r = 0; r < 4; r++) {
            float uk = u[wave][r][k];
            a0[r] = fmaf(uk, e.x, a0[r]);
            a1[r] = fmaf(uk, e.y, a1[r]);
        }
    }
    float bx = ebias[c0], by = ebias[c0 + 1];
    float y2 = waveRedSum(bx*bx + by*by);          // row-invariant
    #pragma unroll
    for (int r = 0; r < 4; r++)
        tangent_pack(a0[r], a1[r], bx, by, y2, row0 + r, c0, vpack);
}

// ---------------------------------------------------------------------------
// Kernel B: t = adj @ v  (bf16 MFMA, fp32 out), DMA pipeline.
// Verified structure (rounds 3/5) — UNCHANGED; three compute-side variants
// were flat, so kB sits at its HBM floor (~50 us for the 268 MB adj read).
//  - adj tile DMA'd HBM->LDS as fp32 (global_load_lds width 16), dbuf;
//    DMA drains only at the iter-end __syncthreads.
//  - 16B chunks XOR-swizzled via the per-lane *global source* address
//    (linear DMA dest); reads apply the same XOR.
//  - fp32 -> bf16 on read via v_cvt_pk_bf16_f32.
//  - B fragments preloaded before DMA issue so their vmcnt waits never
//    force the DMA queue (in-order, oldest-first) to drain.
// ---------------------------------------------------------------------------
#define BK 128

__global__ __launch_bounds__(256, 4) void kB(const float* __restrict__ adj,
                                             const unsigned short* __restrict__ vpack,
                                             float* __restrict__ tpart,
                                             int klen) {
    __shared__ __align__(16) float Af[2][32][128];   // 2 x 16 KB
    const int tid  = threadIdx.x;
    const int wave = tid >> 6;
    const int lane = tid & 63;
    const int r0   = blockIdx.x * 32;
    const int k0   = blockIdx.y * klen;
    float* tout    = tpart + (size_t)blockIdx.y * 8192 * 128;

    // DMA: issue i = wave*4+j covers LDS rows {2i, 2i+1} (1 KB each issue).
    const int rpar = lane >> 5;
    const int cst  = lane & 31;

    // MFMA fragment indexing
    const int m  = lane & 31;       // A row / output row-within-tile
    const int kh = lane >> 5;       // k-half
    const int n  = wave * 32 + m;   // output col
    const int sw = m & 7;           // read-side chunk swizzle
    const unsigned short* vb = vpack + (size_t)n * 16 + kh * 8;

    f32x16 acc = {0.f};
    const int kiters = klen / BK;

    // prologue: DMA tile 0 -> buf 0
    #pragma unroll
    for (int j = 0; j < 4; j++) {
        int i = wave * 4 + j;
        int r = 2 * i + rpar;
        const float* src = adj + (size_t)(r0 + r) * 8192 + k0 + ((cst ^ (r & 7)) << 2);
        async_cp16(src, (char*)&Af[0][0][0] + i * 1024);
    }
    __syncthreads();

    for (int it = 0; it < kiters; it++) {
        const int cur = it & 1;
        const int ktile0 = (k0 + it * BK) >> 4;

        // (1) preload this tile's B fragments (oldest in vmcnt queue)
        s16x8 bfr[8];
        #pragma unroll
        for (int kk = 0; kk < 8; kk++)
            bfr[kk] = *(const s16x8*)(vb + (size_t)(ktile0 + kk) * 2048);

        // (2) issue DMA for tile it+1 into the other buffer
        if (it + 1 < kiters) {
            #pragma unroll
            for (int j = 0; j < 4; j++) {
                int i = wave * 4 + j;
                int r = 2 * i + rpar;
                const float* src = adj + (size_t)(r0 + r) * 8192 + k0 + (it + 1) * BK
                                 + ((cst ^ (r & 7)) << 2);
                async_cp16(src, (char*)&Af[cur ^ 1][0][0] + i * 1024);
            }
        }

        // (3) compute on buf cur: swizzled ds_read, cvt_pk, MFMA
        #pragma unroll
        for (int kk = 0; kk < 8; kk++) {
            const int q0 = kk * 4 + kh * 2;
            const float4 lo = *(const float4*)&Af[cur][m][(q0 ^ sw) << 2];
            const float4 hi = *(const float4*)&Af[cur][m][((q0 + 1) ^ sw) << 2];
            union { unsigned u[4]; s16x8 v; } p;
            p.u[0] = cvt_pk_bf16(lo.x, lo.y);
            p.u[1] = cvt_pk_bf16(lo.z, lo.w);
            p.u[2] = cvt_pk_bf16(hi.x, hi.y);
            p.u[3] = cvt_pk_bf16(hi.z, hi.w);
            acc = __builtin_amdgcn_mfma_f32_32x32x16_bf16(p.v, bfr[kk], acc, 0, 0, 0);
        }

        __syncthreads();   // drains DMA (vmcnt 0) + all readers done with cur
    }

    // epilogue: C/D layout col=lane&31, row=(r&3)+8*(r>>2)+4*(lane>>5)
    #pragma unroll
    for (int r = 0; r < 16; r++) {
        int row = r0 + (r & 3) + 8 * (r >> 2) + 4 * kh;
        tout[(size_t)row * 128 + n] = acc[r];
    }
}

// ---------------------------------------------------------------------------
// Kernel C: out = h_add( exp0( log0([x ; exp0(sum tpart)]) @ layer ), lbias )
// 4 rows/wave: quarters layer L2 traffic (1 GB -> 256 MB vs 1-row).
// ---------------------------------------------------------------------------
#define SPLITS 8

__global__ __launch_bounds__(256) void kC(const float* __restrict__ x,
                                          const float* __restrict__ tpart,
                                          const float* __restrict__ layer,
                                          const float* __restrict__ lbias,
                                          float* __restrict__ out) {
    __shared__ float w[4][4][256];
    const int wave = threadIdx.x >> 6;
    const int lane = threadIdx.x & 63;
    const int row0 = blockIdx.x * 16 + wave * 4;   // rows row0 .. row0+3
    const int c0   = lane * 2;

    #pragma unroll
    for (int r = 0; r < 4; r++) {
        const int row = row0 + r;
        float2 tr = *(const float2*)(tpart + (size_t)row * 128 + c0);
        #pragma unroll
        for (int s = 1; s < SPLITS; s++) {
            float2 p = *(const float2*)(tpart + (size_t)s * 8192 * 128
                                        + (size_t)row * 128 + c0);
            tr.x += p.x; tr.y += p.y;
        }
        const float2 xr = *(const float2*)(x + (size_t)row * 128 + c0);
        float st = waveRedSum(tr.x*tr.x + tr.y*tr.y);
        float sx = waveRedSum(xr.x*xr.x + xr.y*xr.y);
        float nt = fmaxf(sqrtf(st), EPS);
        float se = tanhf(nt)/nt;
        float ncat2 = sx + st*se*se;
        float ncat  = fmaxf(sqrtf(ncat2), EPS);
        float swl   = atanhf(fminf(ncat, MAXT))/ncat;
        w[wave][r][c0]         = xr.x*swl;
        w[wave][r][c0+1]       = xr.y*swl;
        w[wave][r][128 + c0]   = tr.x*se*swl;
        w[wave][r][128 + c0+1] = tr.y*se*swl;
    }
    __syncthreads();

    float a0[4] = {0.f,0.f,0.f,0.f}, a1[4] = {0.f,0.f,0.f,0.f};
    #pragma unroll 8
    for (int k = 0; k < 256; k++) {
        float2 e = *(const float2*)(layer + (size_t)k * 128 + c0);
        #pragma unroll
        for (int r = 0; r < 4; r++) {
            float wk = w[wave][r][k];
            a0[r] = fmaf(wk, e.x, a0[r]);
            a1[r] = fmaf(wk, e.y, a1[r]);
        }
    }
    float bx = lbias[c0], by = lbias[c0 + 1];
    float y2 = waveRedSum(bx*bx + by*by);
    #pragma unroll
    for (int r = 0; r < 4; r++)
        final_out(a0[r], a1[r], bx, by, y2, row0 + r, c0, out);
}

// ---------------------------------------------------------------------------
extern "C" void kernel_launch(void* const* d_in, const int* in_sizes, int n_in,
                              void* d_out, int out_size, void* d_ws, size_t ws_size,
                              hipStream_t stream) {
    const float* x     = (const float*)d_in[0];   // [8192,128]
    const float* adj   = (const float*)d_in[1];   // [8192,8192]
    const float* embed = (const float*)d_in[2];   // [128,128]
    const float* layer = (const float*)d_in[3];   // [256,128]
    const float* eb    = (const float*)d_in[4];   // [128]
    const float* lb    = (const float*)d_in[5];   // [128]
    float* out = (float*)d_out;

    const size_t vbytes = (size_t)8192 * 128 * 2;          // 2 MB bf16 packed
    unsigned short* vpack = (unsigned short*)d_ws;
    float* tpart = (float*)((char*)d_ws + vbytes);

    kA<<<512, 256, 0, stream>>>(x, embed, eb, vpack);
    kB<<<dim3(256, SPLITS), 256, 0, stream>>>(adj, vpack, tpart, 8192 / SPLITS);
    kC<<<512, 256, 0, stream>>>(x, tpart, layer, lb, out);
}